// Round 1
// baseline (82.585 us; speedup 1.0000x reference)
//
#include <hip/hip_runtime.h>
#include <math.h>

#define HH 256
#define WW 256
#define BB 8
#define NTOT (BB*HH*WW)
#define LARGE_F 1000000.0f

typedef unsigned int u32;
typedef unsigned long long u64;

// THREE stream-ordered dispatches replace the old single-dispatch poison-keyed
// spin design. Dispatch boundaries provide all cross-block sync (runtime
// flush/inv between kernels), so there are NO spins, NO device-scope atomics,
// NO poison checks. k1: EDT + focal + per-slab maxima + signed-dist store.
// k2: md reduce + weights + IoU partials. k3: deterministic final gather
// (identical tree to the old block-0 code => bit-identical result).

__device__ __forceinline__ float wave_max(float v) {
    #pragma unroll
    for (int off = 32; off > 0; off >>= 1)
        v = fmaxf(v, __shfl_xor(v, off, 64));
    return v;
}

// ballot-build row's 256-bit mask into LDS (wave-uniform call; 64 lanes active)
__device__ __forceinline__ void build_row(const int* __restrict__ tgt, int tb,
                                          int row, int lane, u64 (*sm)[4]) {
    const int base = tb + (row << 8) + lane;
    u64 w0 = __ballot(tgt[base]       == 0);
    u64 w1 = __ballot(tgt[base + 64]  == 0);
    u64 w2 = __ballot(tgt[base + 128] == 0);
    u64 w3 = __ballot(tgt[base + 192] == 0);
    if (lane == 0) { sm[row][0] = w0; sm[row][1] = w1; sm[row][2] = w2; sm[row][3] = w3; }
}

// nearest set-bit distances within one 256-bit row mask (bit set = feature)
__device__ __forceinline__ void row_check(const u64* __restrict__ row,
                                          int k0, int r0, int c0, float dh2f,
                                          float* bestA, float* bestB) {
    u64 m0 = row[0], m1 = row[1], m2 = row[2], m3 = row[3];
    u64 n0 = ~m0, n1 = ~m1, n2 = ~m2, n3 = ~m3;

    int HbA = -1;
    if (k0 > 0 && m0) HbA = 63  - __builtin_clzll(m0);
    if (k0 > 1 && m1) HbA = 127 - __builtin_clzll(m1);
    if (k0 > 2 && m2) HbA = 191 - __builtin_clzll(m2);
    int RaA = 1 << 20;
    if (k0 < 3 && m3) RaA = 192 + __builtin_ctzll(m3);
    if (k0 < 2 && m2) RaA = 128 + __builtin_ctzll(m2);
    if (k0 < 1 && m1) RaA = 64  + __builtin_ctzll(m1);

    int HbB = -1;
    if (k0 > 0 && n0) HbB = 63  - __builtin_clzll(n0);
    if (k0 > 1 && n1) HbB = 127 - __builtin_clzll(n1);
    if (k0 > 2 && n2) HbB = 191 - __builtin_clzll(n2);
    int RaB = 1 << 20;
    if (k0 < 3 && n3) RaB = 192 + __builtin_ctzll(n3);
    if (k0 < 2 && n2) RaB = 128 + __builtin_ctzll(n2);
    if (k0 < 1 && n1) RaB = 64  + __builtin_ctzll(n1);

    u64 mk = (k0 == 0) ? m0 : (k0 == 1) ? m1 : (k0 == 2) ? m2 : m3;
    u64 nk = ~mk;
    const int base = 64 * k0;

    #pragma unroll
    for (int s = 0; s < 4; ++s) {
        int r = r0 + s, w = c0 + s;
        u64 le = (2ull << r) - 1ull;
        u64 ge = (~0ull) << r;
        {
            u64 lo = mk & le, hi = mk & ge;
            int L = lo ? (base + 63 - __builtin_clzll(lo)) : HbA;
            int R = hi ? (base + __builtin_ctzll(hi)) : RaA;
            int dl = (L >= 0) ? (w - L) : (1 << 20);
            int dr = R - w;
            float f = (float)min(dl, dr);
            bestA[s] = fminf(bestA[s], __builtin_fmaf(f, f, dh2f));
        }
        {
            u64 lo = nk & le, hi = nk & ge;
            int L = lo ? (base + 63 - __builtin_clzll(lo)) : HbB;
            int R = hi ? (base + __builtin_ctzll(hi)) : RaB;
            int dl = (L >= 0) ? (w - L) : (1 << 20);
            int dr = R - w;
            float f = (float)min(dl, dr);
            bestB[s] = fminf(bestB[s], __builtin_fmaf(f, f, dh2f));
        }
    }
}

// ---------------- kernel 1: EDT + focal + slab maxima + signed-dist ----------
__global__ void __launch_bounds__(512) k_edt_focal(
    const float* __restrict__ p0, const float* __restrict__ p1,
    const float* __restrict__ p2, const float* __restrict__ p3,
    const int* __restrict__ tgt,
    u64* __restrict__ slabAB, float* __restrict__ partial,
    float* __restrict__ sdbuf)
{
    const int blk  = blockIdx.x;
    const int b    = blk >> 5;        // image (32 blocks per image)
    const int slab = blk & 31;        // 8-row slab
    const int wv   = threadIdx.x >> 6;
    const int lane = threadIdx.x & 63;
    const int h    = slab * 8 + wv;   // this wave's row
    const int c0   = lane * 4;
    const int k0   = c0 >> 6;
    const int r0   = c0 & 63;
    const int tb   = b << 16;
    const int idx  = tb + (h << 8) + c0;

    __shared__ u64 sm[HH][4];
    __shared__ float wredA[8], wredB[8];
    __shared__ float red[8][4];

    // cooperative initial window: rows [slab*8-8, slab*8+15], 3 rows/wave
    const int lo0 = slab * 8 - 8;
    #pragma unroll
    for (int j = 0; j < 3; ++j) {
        int row = lo0 + wv * 3 + j;
        if (row >= 0 && row < HH) build_row(tgt, tb, row, lane, sm);
    }

    // pred loads issued now; consumed after EDT
    float4 x40 = *(const float4*)(p0 + idx);
    float4 x41 = *(const float4*)(p1 + idx);
    float4 x42 = *(const float4*)(p2 + idx);
    float4 x43 = *(const float4*)(p3 + idx);

    __syncthreads();
    int winLo = max(lo0, 0);
    int winHi = min(lo0 + 23, HH - 1);

    // EDT ring search (wave-uniform loop, lazy row extension)
    float bestA[4] = {1e30f, 1e30f, 1e30f, 1e30f};
    float bestB[4] = {1e30f, 1e30f, 1e30f, 1e30f};

    row_check(&sm[h][0], k0, r0, c0, 0.0f, bestA, bestB);
    float bmax = 0.0f;
    #pragma unroll
    for (int s = 0; s < 4; ++s) bmax = fmaxf(bmax, fmaxf(bestA[s], bestB[s]));
    float wbmax = wave_max(bmax);

    for (int dh = 1; dh < HH; ++dh) {
        float dh2f = (float)(dh * dh);
        if (dh2f >= wbmax) break;                 // uniform on all lanes
        int hd = h - dh, hu = h + dh;
        if (hd >= 0) {
            if (hd < winLo) { build_row(tgt, tb, hd, lane, sm); winLo = hd; }
            row_check(&sm[hd][0], k0, r0, c0, dh2f, bestA, bestB);
        }
        if (hu < HH) {
            if (hu > winHi) { build_row(tgt, tb, hu, lane, sm); winHi = hu; }
            row_check(&sm[hu][0], k0, r0, c0, dh2f, bestA, bestB);
        }
        bmax = 0.0f;
        #pragma unroll
        for (int s = 0; s < 4; ++s) bmax = fmaxf(bmax, fmaxf(bestA[s], bestB[s]));
        wbmax = wave_max(bmax);
    }

    // per-pixel signed dist (sign encodes t: + => t==1 (dist=dA), - => t==0
    // (dist=dB)). |sd| >= 1 always, so sign is well-defined.
    const u64 mkown = sm[h][k0];
    float tfv[4], sdv[4];
    float wmA = -1.0f, wmB = -1.0f;
    #pragma unroll
    for (int s = 0; s < 4; ++s) {
        float dA = (bestA[s] >= 1e29f) ? LARGE_F : sqrtf(bestA[s]);
        float dB = (bestB[s] >= 1e29f) ? LARGE_F : sqrtf(bestB[s]);
        wmA = fmaxf(wmA, dA);
        wmB = fmaxf(wmB, dB);
        int bit = (int)((mkown >> (r0 + s)) & 1ull);   // set => t==0
        tfv[s] = bit ? 0.0f : 1.0f;
        sdv[s] = bit ? -dB : dA;
    }
    float4 sd4; sd4.x = sdv[0]; sd4.y = sdv[1]; sd4.z = sdv[2]; sd4.w = sdv[3];
    *(float4*)(sdbuf + idx) = sd4;

    #pragma unroll
    for (int off = 32; off > 0; off >>= 1) {
        wmA = fmaxf(wmA, __shfl_down(wmA, off, 64));
        wmB = fmaxf(wmB, __shfl_down(wmB, off, 64));
    }
    if (lane == 0) { wredA[wv] = wmA; wredB[wv] = wmB; }

    // focal partials (md-independent); ce identity: ce = (1-t)*x - log_sig(x)
    float vals[4] = {0.0f, 0.0f, 0.0f, 0.0f};
    #pragma unroll
    for (int s = 0; s < 4; ++s) {
        float tf = tfv[s];
        #pragma unroll
        for (int i = 0; i < 4; ++i) {
            float x = (s == 0) ? ((i==0)?x40.x:(i==1)?x41.x:(i==2)?x42.x:x43.x)
                    : (s == 1) ? ((i==0)?x40.y:(i==1)?x41.y:(i==2)?x42.y:x43.y)
                    : (s == 2) ? ((i==0)?x40.z:(i==1)?x41.z:(i==2)?x42.z:x43.z)
                               : ((i==0)?x40.w:(i==1)?x41.w:(i==2)?x42.w:x43.w);
            float e = __expf(-x);                       // e^{-x}
            float p = __builtin_amdgcn_rcpf(1.0f + e);  // sigmoid
            float emabs = (x >= 0.0f) ? e : __builtin_amdgcn_rcpf(e);  // e^{-|x|}
            float ls = fminf(x, 0.0f) - __logf(1.0f + emabs);          // log_sigmoid(x)
            float ce = (1.0f - tf) * x - ls;
            float p_t = p * tf + (1.0f - p) * (1.0f - tf);
            float om = 1.0f - p_t;
            float alpha_t = 0.25f * tf + 0.75f * (1.0f - tf);
            vals[i] += alpha_t * om * om * ce;
        }
    }
    #pragma unroll
    for (int q = 0; q < 4; ++q) {
        float v = vals[q];
        #pragma unroll
        for (int o = 32; o > 0; o >>= 1) v += __shfl_down(v, o, 64);
        if (lane == 0) red[wv][q] = v;
    }
    __syncthreads();
    if (threadIdx.x == 0) {
        float bA = wredA[0], bB = wredB[0];
        #pragma unroll
        for (int j = 1; j < 8; ++j) {
            bA = fmaxf(bA, wredA[j]);
            bB = fmaxf(bB, wredB[j]);
        }
        slabAB[blk] = ((u64)__float_as_uint(bB) << 32) | (u64)__float_as_uint(bA);
    }
    if (threadIdx.x < 4) {
        int q = threadIdx.x;
        float s = 0.0f;
        #pragma unroll
        for (int j = 0; j < 8; ++j) s += red[j][q];
        partial[blk * 12 + q] = s;
    }
}

// ---------------- kernel 2: md reduce + weights + IoU partials ---------------
__global__ void __launch_bounds__(512) k_iou(
    const float* __restrict__ p0, const float* __restrict__ p1,
    const float* __restrict__ p2, const float* __restrict__ p3,
    const u64* __restrict__ slabAB, float* __restrict__ partial,
    const float* __restrict__ sdbuf)
{
    const int blk  = blockIdx.x;
    const int b    = blk >> 5;
    const int slab = blk & 31;
    const int wv   = threadIdx.x >> 6;
    const int lane = threadIdx.x & 63;
    const int h    = slab * 8 + wv;
    const int c0   = lane * 4;
    const int idx  = (b << 16) + (h << 8) + c0;

    __shared__ float smdv[2];
    __shared__ float red[8][8];

    if (threadIdx.x < 32) {
        u64 v = slabAB[(b << 5) + threadIdx.x];
        float a  = __uint_as_float((u32)v);
        float bb = __uint_as_float((u32)(v >> 32));
        #pragma unroll
        for (int off = 16; off > 0; off >>= 1) {
            a  = fmaxf(a,  __shfl_xor(a,  off, 32));
            bb = fmaxf(bb, __shfl_xor(bb, off, 32));
        }
        if (threadIdx.x == 0) { smdv[0] = a; smdv[1] = bb; }
    }

    float4 x40 = *(const float4*)(p0 + idx);
    float4 x41 = *(const float4*)(p1 + idx);
    float4 x42 = *(const float4*)(p2 + idx);
    float4 x43 = *(const float4*)(p3 + idx);
    float4 sd4 = *(const float4*)(sdbuf + idx);

    __syncthreads();
    const float wB = smdv[1];
    const float md = fmaxf(smdv[0], wB);
    // wB == exactly 1e6 iff the image has no t==1 pixels (real dists < 361)
    const bool valid = (wB != LARGE_F) && (md > 0.0f);
    const float inv = 3.0f / fmaxf(md, 1e-12f);

    float vals[8];
    #pragma unroll
    for (int q = 0; q < 8; ++q) vals[q] = 0.0f;

    #pragma unroll
    for (int s = 0; s < 4; ++s) {
        float sd = (s == 0) ? sd4.x : (s == 1) ? sd4.y : (s == 2) ? sd4.z : sd4.w;
        float tf = (sd > 0.0f) ? 1.0f : 0.0f;
        float absd = fabsf(sd);
        float wgt = valid ? (1.0f + __expf(-absd * inv)) : 1.0f;
        #pragma unroll
        for (int i = 0; i < 4; ++i) {
            float x = (s == 0) ? ((i==0)?x40.x:(i==1)?x41.x:(i==2)?x42.x:x43.x)
                    : (s == 1) ? ((i==0)?x40.y:(i==1)?x41.y:(i==2)?x42.y:x43.y)
                    : (s == 2) ? ((i==0)?x40.z:(i==1)?x41.z:(i==2)?x42.z:x43.z)
                               : ((i==0)?x40.w:(i==1)?x41.w:(i==2)?x42.w:x43.w);
            float e = __expf(-x);
            float p = __builtin_amdgcn_rcpf(1.0f + e);  // same ops as k1 => bit-identical
            vals[i]     += tf * p * wgt;
            vals[4 + i] += (p + tf) * wgt;
        }
    }

    #pragma unroll
    for (int q = 0; q < 8; ++q) {
        float v = vals[q];
        #pragma unroll
        for (int o = 32; o > 0; o >>= 1) v += __shfl_down(v, o, 64);
        if (lane == 0) red[wv][q] = v;
    }
    __syncthreads();
    if (threadIdx.x < 8) {
        int q = threadIdx.x;
        float s = 0.0f;
        #pragma unroll
        for (int j = 0; j < 8; ++j) s += red[j][q];
        partial[blk * 12 + 4 + q] = s;
    }
}

// ---------------- kernel 3: deterministic final gather (old block-0 tree) ----
__global__ void k_final(const float* __restrict__ partial, float* __restrict__ out)
{
    __shared__ float fing[96];
    if (threadIdx.x < 96) {
        const int bi = threadIdx.x / 12;   // image
        const int qq = threadIdx.x % 12;
        float acc8[8];
        #pragma unroll
        for (int j = 0; j < 8; ++j) acc8[j] = 0.0f;
        #pragma unroll
        for (int g4 = 0; g4 < 4; ++g4) {
            #pragma unroll
            for (int j = 0; j < 8; ++j)
                acc8[j] += partial[((bi << 5) + g4 * 8 + j) * 12 + qq];
        }
        fing[threadIdx.x] = ((acc8[0]+acc8[1])+(acc8[2]+acc8[3]))
                          + ((acc8[4]+acc8[5])+(acc8[6]+acc8[7]));
    }
    __syncthreads();
    if (threadIdx.x == 0) {
        const float coef[4] = {1.0f, 0.4f, 0.2f, 0.4f / 3.0f};
        float total = 0.0f;
        #pragma unroll
        for (int i = 0; i < 4; ++i) {
            float fm = 0.0f, ious = 0.0f;
            #pragma unroll
            for (int b2 = 0; b2 < BB; ++b2) {
                fm += fing[b2 * 12 + i];
                float in_ = fing[b2 * 12 + 4 + i];
                float un  = fing[b2 * 12 + 8 + i] - in_;
                ious += (in_ + 1e-6f) / (un + 1e-6f);
            }
            total += coef[i] * (fm / (float)NTOT + (1.0f - ious * 0.125f));
        }
        out[0] = total;
    }
}

extern "C" void kernel_launch(void* const* d_in, const int* in_sizes, int n_in,
                              void* d_out, int out_size, void* d_ws, size_t ws_size,
                              hipStream_t stream) {
    const float* p0 = (const float*)d_in[0];
    const float* p1 = (const float*)d_in[1];
    const float* p2 = (const float*)d_in[2];
    const float* p3 = (const float*)d_in[3];
    const int* tgt = (const int*)d_in[4];
    float* out = (float*)d_out;

    char* w = (char*)d_ws;
    u64* slabAB    = (u64*)w;   w += 256 * sizeof(u64);          // 2048 B
    float* partial = (float*)w; w += 256 * 12 * sizeof(float);   // 12288 B
    float* sdbuf   = (float*)w;                                  // 2 MB (16B-aligned)

    k_edt_focal<<<BB * 32, 512, 0, stream>>>(p0, p1, p2, p3, tgt,
                                             slabAB, partial, sdbuf);
    k_iou<<<BB * 32, 512, 0, stream>>>(p0, p1, p2, p3,
                                       slabAB, partial, sdbuf);
    k_final<<<1, 128, 0, stream>>>(partial, out);
}

// Round 2
// 79.345 us; speedup vs baseline: 1.0408x; 1.0408x over previous
//
#include <hip/hip_runtime.h>
#include <math.h>

#define HH 256
#define WW 256
#define BB 8
#define NTOT (BB*HH*WW)
#define LARGE_F 1000000.0f
#define SCOPE __HIP_MEMORY_SCOPE_AGENT

typedef unsigned int u32;
typedef unsigned long long u64;

// Single dispatch (fewest graph nodes — R1 measured ~1us per extra node).
// 256 blocks x 512 threads, 1 row/wave, 4 px/lane, 32 blocks/image.
// Cross-block sync is poison-keyed (published values are nonneg floats; 0xAA
// poison has sign bits set => sign-clear == ready). CE uses the identity
// log_sig(-x) = log_sig(x) - x.
// vs R0: row_check searches ONLY the opposite-class mask per pixel (the
// reference consumes only that distance: dist = where(t, fg, -bg), and
// fg.max/bg.max reduce to maxima of those same selected values) — ~35% of
// the EDT inner work removed, arithmetic bit-identical on surviving values.

__device__ __forceinline__ float wave_max(float v) {
    #pragma unroll
    for (int off = 32; off > 0; off >>= 1)
        v = fmaxf(v, __shfl_xor(v, off, 64));
    return v;
}

// ballot-build row's 256-bit mask into LDS (wave-uniform call; 64 lanes active)
__device__ __forceinline__ void build_row(const int* __restrict__ tgt, int tb,
                                          int row, int lane, u64 (*sm)[4]) {
    const int base = tb + (row << 8) + lane;
    u64 w0 = __ballot(tgt[base]       == 0);
    u64 w1 = __ballot(tgt[base + 64]  == 0);
    u64 w2 = __ballot(tgt[base + 128] == 0);
    u64 w3 = __ballot(tgt[base + 192] == 0);
    if (lane == 0) { sm[row][0] = w0; sm[row][1] = w1; sm[row][2] = w2; sm[row][3] = w3; }
}

// nearest set-bit distance within one 256-bit row mask, own-class-selected:
// pixel s searches n (t==1 set) if its own bit is set (t==0), else m (t==0 set).
__device__ __forceinline__ void row_check1(const u64* __restrict__ row,
                                           int k0, int r0, int c0, float dh2f,
                                           const bool* __restrict__ useN,
                                           float* __restrict__ best) {
    u64 m0 = row[0], m1 = row[1], m2 = row[2], m3 = row[3];
    u64 n0 = ~m0, n1 = ~m1, n2 = ~m2, n3 = ~m3;

    int HbM = -1;
    if (k0 > 0 && m0) HbM = 63  - __builtin_clzll(m0);
    if (k0 > 1 && m1) HbM = 127 - __builtin_clzll(m1);
    if (k0 > 2 && m2) HbM = 191 - __builtin_clzll(m2);
    int RaM = 1 << 20;
    if (k0 < 3 && m3) RaM = 192 + __builtin_ctzll(m3);
    if (k0 < 2 && m2) RaM = 128 + __builtin_ctzll(m2);
    if (k0 < 1 && m1) RaM = 64  + __builtin_ctzll(m1);

    int HbN = -1;
    if (k0 > 0 && n0) HbN = 63  - __builtin_clzll(n0);
    if (k0 > 1 && n1) HbN = 127 - __builtin_clzll(n1);
    if (k0 > 2 && n2) HbN = 191 - __builtin_clzll(n2);
    int RaN = 1 << 20;
    if (k0 < 3 && n3) RaN = 192 + __builtin_ctzll(n3);
    if (k0 < 2 && n2) RaN = 128 + __builtin_ctzll(n2);
    if (k0 < 1 && n1) RaN = 64  + __builtin_ctzll(n1);

    u64 mk = (k0 == 0) ? m0 : (k0 == 1) ? m1 : (k0 == 2) ? m2 : m3;
    u64 nk = ~mk;
    const int base = 64 * k0;

    #pragma unroll
    for (int s = 0; s < 4; ++s) {
        int r = r0 + s, w = c0 + s;
        u64 le = (2ull << r) - 1ull;
        u64 ge = (~0ull) << r;
        u64 sel = useN[s] ? nk : mk;
        int Hb  = useN[s] ? HbN : HbM;
        int Ra  = useN[s] ? RaN : RaM;
        u64 lo = sel & le, hi = sel & ge;
        int L = lo ? (base + 63 - __builtin_clzll(lo)) : Hb;
        int R = hi ? (base + __builtin_ctzll(hi)) : Ra;
        int dl = (L >= 0) ? (w - L) : (1 << 20);
        int dr = R - w;
        float f = (float)min(dl, dr);
        best[s] = fminf(best[s], __builtin_fmaf(f, f, dh2f));
    }
}

__global__ void __launch_bounds__(512) k_fused(
    const float* __restrict__ p0, const float* __restrict__ p1,
    const float* __restrict__ p2, const float* __restrict__ p3,
    const int* __restrict__ tgt,
    u64* __restrict__ slabAB, float* __restrict__ partial,
    float* __restrict__ out)
{
    const int blk  = blockIdx.x;
    const int b    = blk >> 5;        // image (32 blocks per image)
    const int slab = blk & 31;        // 8-row slab
    const int wv   = threadIdx.x >> 6;   // 0..7
    const int lane = threadIdx.x & 63;
    const int h    = slab * 8 + wv;   // this wave's row
    const int c0   = lane * 4;
    const int k0   = c0 >> 6;
    const int r0   = c0 & 63;
    const int tb   = b << 16;
    const int rowbase = tb + (h << 8);

    __shared__ u64 sm[HH][4];
    __shared__ float wredA[8], wredB[8], smdv[2];
    __shared__ float red[8][12];
    __shared__ float fing[96];

    // ---- cooperative initial window FIRST (critical path into EDT):
    //      rows [slab*8-8, slab*8+15], 3 rows per wave ----
    const int lo0 = slab * 8 - 8;
    #pragma unroll
    for (int j = 0; j < 3; ++j) {
        int row = lo0 + wv * 3 + j;
        if (row >= 0 && row < HH) build_row(tgt, tb, row, lane, sm);
    }

    // ---- pred loads issued now; consumed only after EDT ----
    const int idx = rowbase + c0;
    float4 x40 = *(const float4*)(p0 + idx);
    float4 x41 = *(const float4*)(p1 + idx);
    float4 x42 = *(const float4*)(p2 + idx);
    float4 x43 = *(const float4*)(p3 + idx);

    __syncthreads();
    int winLo = max(lo0, 0);
    int winHi = min(lo0 + 23, HH - 1);

    // own-class selection (own row is in the initial window)
    const u64 mkown = sm[h][k0];
    bool useN[4];
    float tfv[4];
    #pragma unroll
    for (int s = 0; s < 4; ++s) {
        int bit = (int)((mkown >> (r0 + s)) & 1ull);   // set => t==0
        useN[s] = (bit != 0);                          // t==0 searches t==1 set
        tfv[s]  = bit ? 0.0f : 1.0f;
    }

    // ---- EDT ring search (wave-uniform loop, lazy row extension) ----
    float best[4] = {1e30f, 1e30f, 1e30f, 1e30f};

    row_check1(&sm[h][0], k0, r0, c0, 0.0f, useN, best);
    float bmax = fmaxf(fmaxf(best[0], best[1]), fmaxf(best[2], best[3]));
    float wbmax = wave_max(bmax);

    for (int dh = 1; dh < HH; ++dh) {
        float dh2f = (float)(dh * dh);
        if (dh2f >= wbmax) break;                 // uniform on all lanes
        int hd = h - dh, hu = h + dh;
        if (hd >= 0) {
            if (hd < winLo) { build_row(tgt, tb, hd, lane, sm); winLo = hd; }
            row_check1(&sm[hd][0], k0, r0, c0, dh2f, useN, best);
        }
        if (hu < HH) {
            if (hu > winHi) { build_row(tgt, tb, hu, lane, sm); winHi = hu; }
            row_check1(&sm[hu][0], k0, r0, c0, dh2f, useN, best);
        }
        bmax = fmaxf(fmaxf(best[0], best[1]), fmaxf(best[2], best[3]));
        wbmax = wave_max(bmax);
    }

    // per-pixel |dist| + class-restricted maxima (fg=0 at t==0 px, bg=0 at
    // t==1 px in the reference, so own-class maxima are exact)
    float absd[4];
    float wmA = 0.0f, wmB = 0.0f;
    #pragma unroll
    for (int s = 0; s < 4; ++s) {
        float d = (best[s] >= 1e29f) ? LARGE_F : sqrtf(best[s]);
        absd[s] = d;
        wmA = fmaxf(wmA, useN[s] ? 0.0f : d);   // max over t==1 px (fg.max)
        wmB = fmaxf(wmB, useN[s] ? d : 0.0f);   // max over t==0 px (bg.max)
    }
    #pragma unroll
    for (int off = 32; off > 0; off >>= 1) {
        wmA = fmaxf(wmA, __shfl_down(wmA, off, 64));
        wmB = fmaxf(wmB, __shfl_down(wmB, off, 64));
    }
    if (lane == 0) { wredA[wv] = wmA; wredB[wv] = wmB; }
    __syncthreads();
    if (threadIdx.x == 0) {
        float bA = wredA[0], bB = wredB[0];
        #pragma unroll
        for (int j = 1; j < 8; ++j) {
            bA = fmaxf(bA, wredA[j]);
            bB = fmaxf(bB, wredB[j]);
        }
        u64 pk = ((u64)__float_as_uint(bB) << 32) | (u64)__float_as_uint(bA);
        __hip_atomic_store(&slabAB[blk], pk, __ATOMIC_RELAXED, SCOPE);
    }

    // ---- md-independent pred math (overlaps peers' skew) ----
    // ce identity: log_sig(-x) = log_sig(x) - x  =>  ce = (1-t)*x - log_sig(x)
    float vals[12];
    #pragma unroll
    for (int q = 0; q < 12; ++q) vals[q] = 0.0f;
    float pv[4][4];
    #pragma unroll
    for (int s = 0; s < 4; ++s) {
        float tf = tfv[s];
        #pragma unroll
        for (int i = 0; i < 4; ++i) {
            float x = (s == 0) ? ((i==0)?x40.x:(i==1)?x41.x:(i==2)?x42.x:x43.x)
                    : (s == 1) ? ((i==0)?x40.y:(i==1)?x41.y:(i==2)?x42.y:x43.y)
                    : (s == 2) ? ((i==0)?x40.z:(i==1)?x41.z:(i==2)?x42.z:x43.z)
                               : ((i==0)?x40.w:(i==1)?x41.w:(i==2)?x42.w:x43.w);
            float e = __expf(-x);                       // e^{-x}
            float p = __builtin_amdgcn_rcpf(1.0f + e);  // sigmoid
            float emabs = (x >= 0.0f) ? e : __builtin_amdgcn_rcpf(e);  // e^{-|x|}
            float ls = fminf(x, 0.0f) - __logf(1.0f + emabs);          // log_sigmoid(x)
            float ce = (1.0f - tf) * x - ls;
            float p_t = p * tf + (1.0f - p) * (1.0f - tf);
            float om = 1.0f - p_t;
            float alpha_t = 0.25f * tf + 0.75f * (1.0f - tf);
            vals[i] += alpha_t * om * om * ce;
            pv[s][i] = p;
        }
    }

    // ---- wait for image md (poison-keyed: both sign bits must be clear) ----
    if (wv == 0) {
        float a = 0.0f, bb = 0.0f;
        if (lane < 32) {
            const int i = (b << 5) + lane;
            u64 v;
            for (;;) {
                v = __hip_atomic_load(&slabAB[i], __ATOMIC_RELAXED, SCOPE);
                if (!(v & 0x8000000080000000ull)) break;
                __builtin_amdgcn_s_sleep(1);
            }
            a  = __uint_as_float((u32)v);
            bb = __uint_as_float((u32)(v >> 32));
        }
        #pragma unroll
        for (int off = 32; off > 0; off >>= 1) {
            a  = fmaxf(a,  __shfl_xor(a,  off, 64));
            bb = fmaxf(bb, __shfl_xor(bb, off, 64));
        }
        if (lane == 0) { smdv[0] = a; smdv[1] = bb; }
    }
    __syncthreads();
    const float wB = smdv[1];
    const float md = fmaxf(smdv[0], wB);
    // wB == exactly 1e6 iff the image has no t==1 pixels (real dists < 361)
    const bool valid = (wB != LARGE_F) && (md > 0.0f);
    const float inv = 3.0f / fmaxf(md, 1e-12f);

    // ---- weights + IoU partials ----
    #pragma unroll
    for (int s = 0; s < 4; ++s) {
        float wgt = valid ? (1.0f + __expf(-absd[s] * inv)) : 1.0f;
        float tf = tfv[s];
        #pragma unroll
        for (int i = 0; i < 4; ++i) {
            vals[4 + i] += tf * pv[s][i] * wgt;
            vals[8 + i] += (pv[s][i] + tf) * wgt;
        }
    }

    // ---- block reduction; publish 12 nonneg partials (self-flagging) ----
    #pragma unroll
    for (int q = 0; q < 12; ++q) {
        float v = vals[q];
        #pragma unroll
        for (int o = 32; o > 0; o >>= 1) v += __shfl_down(v, o, 64);
        if (lane == 0) red[wv][q] = v;
    }
    __syncthreads();
    if (threadIdx.x < 12) {
        int q = threadIdx.x;
        float s = 0.0f;
        #pragma unroll
        for (int j = 0; j < 8; ++j) s += red[j][q];
        __hip_atomic_store((u32*)&partial[blk * 12 + q], __float_as_uint(s),
                           __ATOMIC_RELAXED, SCOPE);
    }

    // ---- block 0: flat final reduction over all 256 blocks ----
    if (blk == 0) {
        if (threadIdx.x < 96) {
            const int bi = threadIdx.x / 12;   // image
            const int qq = threadIdx.x % 12;
            float acc8[8];
            #pragma unroll
            for (int j = 0; j < 8; ++j) acc8[j] = 0.0f;
            for (int g4 = 0; g4 < 4; ++g4) {
                u32 raw[8];
                for (;;) {
                    bool bad = false;
                    #pragma unroll
                    for (int j = 0; j < 8; ++j)
                        raw[j] = __hip_atomic_load((u32*)&partial[((bi << 5) + g4 * 8 + j) * 12 + qq],
                                                   __ATOMIC_RELAXED, SCOPE);
                    #pragma unroll
                    for (int j = 0; j < 8; ++j) bad = bad || ((raw[j] >> 31) != 0u);
                    if (!bad) break;
                    __builtin_amdgcn_s_sleep(1);
                }
                #pragma unroll
                for (int j = 0; j < 8; ++j) acc8[j] += __uint_as_float(raw[j]);
            }
            fing[threadIdx.x] = ((acc8[0]+acc8[1])+(acc8[2]+acc8[3]))
                              + ((acc8[4]+acc8[5])+(acc8[6]+acc8[7]));
        }
        __syncthreads();
        if (threadIdx.x == 0) {
            const float coef[4] = {1.0f, 0.4f, 0.2f, 0.4f / 3.0f};
            float total = 0.0f;
            #pragma unroll
            for (int i = 0; i < 4; ++i) {
                float fm = 0.0f, ious = 0.0f;
                #pragma unroll
                for (int b2 = 0; b2 < BB; ++b2) {
                    fm += fing[b2 * 12 + i];
                    float in_ = fing[b2 * 12 + 4 + i];
                    float un  = fing[b2 * 12 + 8 + i] - in_;
                    ious += (in_ + 1e-6f) / (un + 1e-6f);
                }
                total += coef[i] * (fm / (float)NTOT + (1.0f - ious * 0.125f));
            }
            out[0] = total;
        }
    }
}

extern "C" void kernel_launch(void* const* d_in, const int* in_sizes, int n_in,
                              void* d_out, int out_size, void* d_ws, size_t ws_size,
                              hipStream_t stream) {
    const float* p0 = (const float*)d_in[0];
    const float* p1 = (const float*)d_in[1];
    const float* p2 = (const float*)d_in[2];
    const float* p3 = (const float*)d_in[3];
    const int* tgt = (const int*)d_in[4];
    float* out = (float*)d_out;

    char* w = (char*)d_ws;
    u64* slabAB    = (u64*)w;   w += 256 * sizeof(u64);
    float* partial = (float*)w; w += 256 * 12 * sizeof(float);

    k_fused<<<BB * 32, 512, 0, stream>>>(p0, p1, p2, p3, tgt, slabAB, partial, out);
}